// Round 15
// baseline (438.303 us; speedup 1.0000x reference)
//
#include <hip/hip_runtime.h>

#define DF 128

typedef __attribute__((ext_vector_type(8))) short bf16x8;
typedef __attribute__((ext_vector_type(4))) float f32x4;

__device__ __forceinline__ ushort f2bf(float f) {
  uint u = __float_as_uint(f);
  u += 0x7fff + ((u >> 16) & 1);
  return (ushort)(u >> 16);
}
__device__ __forceinline__ float bfl(uint v) { return __uint_as_float(v << 16); }
__device__ __forceinline__ float bfh(uint v) { return __uint_as_float(v & 0xffff0000u); }
__device__ __forceinline__ float b2f(ushort s) { return __uint_as_float(((uint)s) << 16); }

// ---------------- prepw (fragment-linear weights) + sentinel zeroing ----------------
__global__ __launch_bounds__(256) void prepw_k(const float* __restrict__ W1, const float* __restrict__ W2,
                                               ushort* __restrict__ W1f, ushort* __restrict__ W2f,
                                               ushort* __restrict__ Z3r, ushort* __restrict__ T,
                                               ushort* __restrict__ GBs3, ushort* __restrict__ F0,
                                               ushort* __restrict__ F1, int n) {
  int b = blockIdx.x, tid = threadIdx.x;
  if (b == 256) {       // zero sentinel rows (row n)
    if (tid < 128) {
      Z3r[(size_t)n * 128 + tid] = 0;
      T[(size_t)n * 128 + tid] = 0;
    }
    if (tid < 16) {
      GBs3[(size_t)n * 16 + tid] = 0;
      F0[(size_t)n * 16 + tid] = 0;
      F1[(size_t)n * 16 + tid] = 0;
    }
    return;
  }
  int t = b * 256 + tid;
  {
    int k = t >> 14, rem = t & 16383;
    int frag = rem >> 3, j = rem & 7;
    int nt = frag >> 8, ks = (frag >> 6) & 3, lane = frag & 63;
    int nn = nt * 16 + (lane & 15);
    int kk = ks * 32 + (lane >> 4) * 8 + j;
    W1f[t] = f2bf(W1[k * 16384 + kk * 128 + nn]);
  }
  if (t < 8192) {
    int frag = t >> 3, j = t & 7;
    int nt = frag >> 8, ks = (frag >> 6) & 3, lane = frag & 63;
    int kk = ks * 32 + (lane >> 4) * 8 + j;
    W2f[t] = f2bf(W2[nt * 2048 + kk * 16 + (lane & 15)]);
  }
}

// ---------------- K1: sharded degree hist + per-edge local rank (atomic floor) ----------------
__global__ __launch_bounds__(256) void hist_k(const int* __restrict__ dst, int e,
                                              int* __restrict__ deg_s, int* __restrict__ rank, int n) {
  int i = blockIdx.x * 256 + threadIdx.x;
  if (i < e) {
    int shard = (i >> 8) & 7;
    rank[i] = atomicAdd(&deg_s[(size_t)shard * n + dst[i]], 1);
  }
}

// ---------------- fused reduce + scan1 ----------------
__global__ __launch_bounds__(256) void rs1_k(const int* __restrict__ deg_s, int n,
                                             int* __restrict__ deg, int* __restrict__ P,
                                             float* __restrict__ dis, int* __restrict__ partials) {
  __shared__ int sm[256];
  int tid = threadIdx.x;
  if (blockIdx.x == 0 && tid == 0) dis[n] = 0.f;   // sentinel for hop1's per-edge scale
  int base = blockIdx.x * 1024;
  int s = 0;
#pragma unroll
  for (int j = 0; j < 4; j++) {
    int idx = base + tid * 4 + j;
    if (idx < n) {
      int run = 0;
#pragma unroll
      for (int sh = 0; sh < 8; sh++) {
        int v = deg_s[(size_t)sh * n + idx];
        P[(size_t)sh * n + idx] = run;
        run += v;
      }
      deg[idx] = run;
      dis[idx] = run > 0 ? rsqrtf((float)run) : 0.f;
      s += run;
    }
  }
  sm[tid] = s; __syncthreads();
  for (int off = 128; off > 0; off >>= 1) {
    if (tid < off) sm[tid] += sm[tid + off];
    __syncthreads();
  }
  if (tid == 0) partials[blockIdx.x] = sm[0];
}

// scan3 (self-scans partials) + build base8[sh][d] = rowptr[d] + P[sh][d]
__global__ __launch_bounds__(256) void scan3_k(const int* __restrict__ deg, int n, int e,
                                               const int* __restrict__ partials,
                                               int* __restrict__ rowptr,
                                               const int* __restrict__ P, int* __restrict__ base8) {
  __shared__ int sm[256];
  __shared__ int pp[256];
  int tid = threadIdx.x;
  int pre = 0;
  for (int i = tid; i < blockIdx.x; i += 256) pre += partials[i];
  pp[tid] = pre; __syncthreads();
  for (int off = 128; off > 0; off >>= 1) {
    if (tid < off) pp[tid] += pp[tid + off];
    __syncthreads();
  }
  int blockbase = pp[0];
  int base = blockIdx.x * 1024;
  int loc[4]; int s = 0;
#pragma unroll
  for (int j = 0; j < 4; j++) {
    int idx = base + tid * 4 + j;
    int v = (idx < n) ? deg[idx] : 0;
    loc[j] = s; s += v;
  }
  sm[tid] = s; __syncthreads();
  int tsum = s;
  for (int off = 1; off < 256; off <<= 1) {
    int v = (tid >= (unsigned)off) ? sm[tid - off] : 0;
    __syncthreads();
    sm[tid] += v;
    __syncthreads();
  }
  int excl = sm[tid] - tsum + blockbase;
#pragma unroll
  for (int j = 0; j < 4; j++) {
    int idx = base + tid * 4 + j;
    if (idx < n) {
      int rp = excl + loc[j];
      rowptr[idx] = rp;
#pragma unroll
      for (int sh = 0; sh < 8; sh++)
        base8[(size_t)sh * n + idx] = rp + P[(size_t)sh * n + idx];
    }
  }
  if (blockIdx.x == 0 && tid == 0) rowptr[n] = e;
}

// ---------------- K2: gemmZ blocks [0,GZ) | csr_fill blocks [GZ, GZ+gE) ----------------
__global__ __launch_bounds__(256) void k2_k(const float* __restrict__ x, const ushort* __restrict__ W1f,
                                            ushort* __restrict__ Z3, ushort* __restrict__ Z2,
                                            ushort* __restrict__ Z1, ushort* __restrict__ Z0,
                                            const int* __restrict__ src, const int* __restrict__ dst, int e,
                                            const int* __restrict__ rank, const int* __restrict__ base8,
                                            int* __restrict__ colb, int n, int GZ) {
  int b = blockIdx.x, tid = threadIdx.x;
  if (b >= GZ) {                   // csr_fill role
    int i = (b - GZ) * 256 + tid;
    if (i < e) {
      int d = dst[i];
      int shard = (i >> 8) & 7;
      int p = base8[(size_t)shard * n + d] + rank[i];
      colb[p] = src[i];
    }
    return;
  }
  // gemmZ role: 2 row-fragments per wave, per-nt accumulators (no LDS, low VGPR)
  int wid = tid >> 6, lane = tid & 63;
  int l15 = lane & 15, kgrp = lane >> 4;
  int m0 = b * 128 + wid * 32 + l15;
  int m1 = m0 + 16;
  int mc0 = m0 < n ? m0 : n - 1;
  int mc1 = m1 < n ? m1 : n - 1;
  bf16x8 xf0[4], xf1[4];
#pragma unroll
  for (int ks = 0; ks < 4; ks++) {
    float4 a0 = *reinterpret_cast<const float4*>(x + (size_t)mc0 * 128 + ks * 32 + kgrp * 8);
    float4 a1 = *reinterpret_cast<const float4*>(x + (size_t)mc0 * 128 + ks * 32 + kgrp * 8 + 4);
    float4 b0 = *reinterpret_cast<const float4*>(x + (size_t)mc1 * 128 + ks * 32 + kgrp * 8);
    float4 b1v = *reinterpret_cast<const float4*>(x + (size_t)mc1 * 128 + ks * 32 + kgrp * 8 + 4);
    bf16x8 u, w;
    u[0] = (short)f2bf(a0.x); u[1] = (short)f2bf(a0.y); u[2] = (short)f2bf(a0.z); u[3] = (short)f2bf(a0.w);
    u[4] = (short)f2bf(a1.x); u[5] = (short)f2bf(a1.y); u[6] = (short)f2bf(a1.z); u[7] = (short)f2bf(a1.w);
    w[0] = (short)f2bf(b0.x); w[1] = (short)f2bf(b0.y); w[2] = (short)f2bf(b0.z); w[3] = (short)f2bf(b0.w);
    w[4] = (short)f2bf(b1v.x); w[5] = (short)f2bf(b1v.y); w[6] = (short)f2bf(b1v.z); w[7] = (short)f2bf(b1v.w);
    xf0[ks] = u; xf1[ks] = w;
  }
#pragma unroll
  for (int kk = 0; kk < 4; kk++) {
    const int k = 3 - kk;
    const ushort* Wk = W1f + (size_t)k * 16384;
    ushort* Out = (k == 3) ? Z3 : (k == 2) ? Z2 : (k == 1) ? Z1 : Z0;
#pragma unroll
    for (int nt = 0; nt < 8; nt++) {
      f32x4 acc0 = {0.f, 0.f, 0.f, 0.f}, acc1 = {0.f, 0.f, 0.f, 0.f};
#pragma unroll
      for (int ks = 0; ks < 4; ks++) {
        bf16x8 wf = *reinterpret_cast<const bf16x8*>(Wk + (size_t)((nt * 4 + ks) * 64 + lane) * 8);
        acc0 = __builtin_amdgcn_mfma_f32_16x16x32_bf16(wf, xf0[ks], acc0, 0, 0, 0);
        acc1 = __builtin_amdgcn_mfma_f32_16x16x32_bf16(wf, xf1[ks], acc1, 0, 0, 0);
      }
      int ncol = nt * 16 + kgrp * 4;
      if (m0 < n) {
        ushort4 st; st.x = f2bf(acc0[0]); st.y = f2bf(acc0[1]);
        st.z = f2bf(acc0[2]); st.w = f2bf(acc0[3]);
        *reinterpret_cast<ushort4*>(Out + (size_t)m0 * 128 + ncol) = st;
      }
      if (m1 < n) {
        ushort4 st; st.x = f2bf(acc1[0]); st.y = f2bf(acc1[1]);
        st.z = f2bf(acc1[2]); st.w = f2bf(acc1[3]);
        *reinterpret_cast<ushort4*>(Out + (size_t)m1 * 128 + ncol) = st;
      }
    }
  }
}

// ---------------- hop: both col-halves in one launch; unroll-16; optional per-edge dis scale ----------------
__global__ __launch_bounds__(256) void hop_k(const ushort* __restrict__ hin, const ushort* __restrict__ zk,
                                             const float* __restrict__ b1, ushort* __restrict__ hout,
                                             const int* __restrict__ rowptr, const int* __restrict__ colb,
                                             const float* __restrict__ dis, const float* __restrict__ dscale,
                                             int n, int gHop, int last) {
  int colhalf = blockIdx.x >= gHop ? 1 : 0;
  int nb = blockIdx.x - colhalf * gHop;
  int node = nb * 16 + (threadIdx.x >> 4);
  int gl = threadIdx.x & 15;
  if (node >= n) return;
  int cbase = colhalf * 64 + gl * 4;
  int e0 = rowptr[node], e1 = rowptr[node + 1];
  float a0 = 0.f, a1 = 0.f, a2 = 0.f, a3 = 0.f;
  for (int ee = e0; ee < e1; ee += 16) {
    int c[16];
#pragma unroll
    for (int j = 0; j < 16; j++) {
      int idx = ee + j;
      c[j] = idx < e1 ? colb[idx] : n;      // row n is all-zero sentinel (dis[n]=0 too)
    }
    uint2 v[16];
#pragma unroll
    for (int j = 0; j < 16; j++)
      v[j] = *reinterpret_cast<const uint2*>(hin + (size_t)c[j] * 128 + cbase);
    if (dscale) {
      float w[16];
#pragma unroll
      for (int j = 0; j < 16; j++) w[j] = dscale[c[j]];
#pragma unroll
      for (int j = 0; j < 16; j++) {
        a0 = fmaf(w[j], bfl(v[j].x), a0); a1 = fmaf(w[j], bfh(v[j].x), a1);
        a2 = fmaf(w[j], bfl(v[j].y), a2); a3 = fmaf(w[j], bfh(v[j].y), a3);
      }
    } else {
#pragma unroll
      for (int j = 0; j < 16; j++) {
        a0 += bfl(v[j].x); a1 += bfh(v[j].x);
        a2 += bfl(v[j].y); a3 += bfh(v[j].y);
      }
    }
  }
  float d = dis[node];
  uint2 zr = *reinterpret_cast<const uint2*>(zk + (size_t)node * 128 + cbase);
  float t0 = fmaf(d, a0, bfl(zr.x)), t1 = fmaf(d, a1, bfh(zr.x));
  float t2 = fmaf(d, a2, bfl(zr.y)), t3 = fmaf(d, a3, bfh(zr.y));
  uint2 st;
  if (last) {
    float4 bv = *reinterpret_cast<const float4*>(b1 + cbase);
    t0 = fmaxf(t0 + bv.x, 0.f); t1 = fmaxf(t1 + bv.y, 0.f);
    t2 = fmaxf(t2 + bv.z, 0.f); t3 = fmaxf(t3 + bv.w, 0.f);
    st.x = (uint)f2bf(t0) | ((uint)f2bf(t1) << 16);
    st.y = (uint)f2bf(t2) | ((uint)f2bf(t3) << 16);
  } else {
    st.x = (uint)f2bf(d * t0) | ((uint)f2bf(d * t1) << 16);
    st.y = (uint)f2bf(d * t2) | ((uint)f2bf(d * t3) << 16);
  }
  *reinterpret_cast<uint2*>(hout + (size_t)node * 128 + cbase) = st;
}

// ---------------- final GEMM: GB = h1 @ W2pack (raw) + GBs3 = dis * g3 ----------------
__global__ __launch_bounds__(256) void gemm_last_k(const ushort* __restrict__ h1, const ushort* __restrict__ W2f,
                                                   const float* __restrict__ dis,
                                                   ushort* __restrict__ GB, ushort* __restrict__ GBs3, int n) {
  int wid = threadIdx.x >> 6, lane = threadIdx.x & 63;
  int kgrp = lane >> 4;
  int m = blockIdx.x * 64 + wid * 16 + (lane & 15);
  int mc = m < n ? m : n - 1;
  float dm = dis[mc];
  bf16x8 xf[4];
#pragma unroll
  for (int ks = 0; ks < 4; ks++)
    xf[ks] = *reinterpret_cast<const bf16x8*>(h1 + (size_t)mc * 128 + ks * 32 + kgrp * 8);
#pragma unroll
  for (int nt = 0; nt < 4; nt++) {
    f32x4 acc = {0.f, 0.f, 0.f, 0.f};
#pragma unroll
    for (int ks = 0; ks < 4; ks++) {
      bf16x8 wf = *reinterpret_cast<const bf16x8*>(W2f + (size_t)((nt * 4 + ks) * 64 + lane) * 8);
      acc = __builtin_amdgcn_mfma_f32_16x16x32_bf16(wf, xf[ks], acc, 0, 0, 0);
    }
    if (m < n) {
      int ncol = nt * 16 + kgrp * 4;
      ushort4 st; st.x = f2bf(acc[0]); st.y = f2bf(acc[1]); st.z = f2bf(acc[2]); st.w = f2bf(acc[3]);
      *reinterpret_cast<ushort4*>(GB + (size_t)m * 64 + ncol) = st;
      if (nt == 3) {
        ushort4 ss; ss.x = f2bf(dm * acc[0]); ss.y = f2bf(dm * acc[1]);
        ss.z = f2bf(dm * acc[2]); ss.w = f2bf(dm * acc[3]);
        *reinterpret_cast<ushort4*>(GBs3 + (size_t)m * 16 + kgrp * 4) = ss;
      }
    }
  }
}

// ---------------- SpMM D=16: unroll-8 ----------------
__global__ __launch_bounds__(256) void spmm16_k(const ushort* __restrict__ in,
                                                const ushort* __restrict__ addraw, int addstride,
                                                const float* __restrict__ b2,
                                                float* __restrict__ outf, ushort* __restrict__ outb,
                                                const int* __restrict__ rowptr, const int* __restrict__ colb,
                                                const float* __restrict__ dis, int n) {
  int t = blockIdx.x * 256 + threadIdx.x;
  int node = t >> 3, cp = t & 7;
  if (node >= n) return;
  int e0 = rowptr[node], e1 = rowptr[node + 1];
  float a0 = 0.f, a1 = 0.f;
  for (int ee = e0; ee < e1; ee += 8) {
    int c[8];
#pragma unroll
    for (int j = 0; j < 8; j++) {
      int idx = ee + j;
      c[j] = idx < e1 ? colb[idx] : n;
    }
    uint v[8];
#pragma unroll
    for (int j = 0; j < 8; j++)
      v[j] = *reinterpret_cast<const uint*>(in + (size_t)c[j] * 16 + cp * 2);
#pragma unroll
    for (int j = 0; j < 8; j++) { a0 += bfl(v[j]); a1 += bfh(v[j]); }
  }
  float d = dis[node];
  uint av = *reinterpret_cast<const uint*>(addraw + (size_t)node * addstride + cp * 2);
  float t0 = fmaf(d, a0, b2f((ushort)(av & 0xffff)));
  float t1 = fmaf(d, a1, b2f((ushort)(av >> 16)));
  if (outf) {
    float2 st; st.x = t0 + b2[cp * 2]; st.y = t1 + b2[cp * 2 + 1];
    *reinterpret_cast<float2*>(outf + (size_t)node * 16 + cp * 2) = st;
  } else {
    uint pk = (uint)f2bf(d * t0) | ((uint)f2bf(d * t1) << 16);
    *reinterpret_cast<uint*>(outb + (size_t)node * 16 + cp * 2) = pk;
  }
}

extern "C" void kernel_launch(void* const* d_in, const int* in_sizes, int n_in,
                              void* d_out, int out_size, void* d_ws, size_t ws_size,
                              hipStream_t stream) {
  const float* x  = (const float*)d_in[0];
  const int*   ei = (const int*)d_in[1];
  const float* W1 = (const float*)d_in[2];
  const float* b1 = (const float*)d_in[3];
  const float* W2 = (const float*)d_in[4];
  const float* b2 = (const float*)d_in[5];
  float* out = (float*)d_out;

  const int n = in_sizes[0] / DF;
  const int e = in_sizes[1] / 2;
  const int* srcp = ei;
  const int* dstp = ei + e;

  char* ws = (char*)d_ws;
  size_t off = 0;
  auto alloc = [&](size_t bytes) -> void* {
    void* p = ws + off;
    off += (bytes + 255) & ~(size_t)255;
    return p;
  };
  ushort* Z3r  = (ushort*)alloc((size_t)(n + 1) * 128 * 2); // z3 RAW (hop1 scales per-edge); then hop2 out
  ushort* T    = (ushort*)alloc((size_t)(n + 1) * 128 * 2); // hop1 out; then h1 (hop3 out)
  ushort* Z2   = (ushort*)alloc((size_t)n * 128 * 2);       // later GB (n x 64)
  ushort* Z1   = (ushort*)alloc((size_t)n * 128 * 2);
  ushort* Z0   = (ushort*)alloc((size_t)n * 128 * 2);
  int*   deg_s = (int*)alloc((size_t)8 * n * 4);            // sharded hist; later base8
  int*   P     = (int*)alloc((size_t)8 * n * 4);
  int*   deg   = (int*)alloc((size_t)n * 4);
  float* dis   = (float*)alloc((size_t)(n + 1) * 4);        // +1 sentinel (=0)
  int*   rowptr= (int*)alloc((size_t)(n + 1) * 4);
  int*   rank  = (int*)alloc((size_t)e * 4);
  int*   partials = (int*)alloc(1024 * 4);
  int*   colb  = (int*)alloc((size_t)e * 4);
  ushort* W1f  = (ushort*)alloc(4 * 128 * 128 * 2);
  ushort* W2f  = (ushort*)alloc(64 * 128 * 2);
  ushort* GBs3 = (ushort*)alloc((size_t)(n + 1) * 16 * 2);
  ushort* F0   = (ushort*)alloc((size_t)(n + 1) * 16 * 2);
  ushort* F1   = (ushort*)alloc((size_t)(n + 1) * 16 * 2);
  // aliases
  ushort* Up = Z3r;   // hop2 output (Z3r consumed by hop1)
  ushort* h1 = T;     // hop3 output (T consumed by hop2)
  ushort* GB = Z2;    // gemm_last output (Z2 consumed by hop1's zk)
  int* base8 = deg_s; // scan3 output (deg_s dead after rs1)

  hipMemsetAsync(deg_s, 0, (size_t)8 * n * 4, stream);

  int gE = (e + 255) / 256;
  int nb = (n + 1023) / 1024;
  int GZ = (n + 127) / 128;

  prepw_k<<<257, 256, 0, stream>>>(W1, W2, W1f, W2f, Z3r, T, GBs3, F0, F1, n);
  hist_k<<<gE, 256, 0, stream>>>(dstp, e, deg_s, rank, n);
  rs1_k<<<nb, 256, 0, stream>>>(deg_s, n, deg, P, dis, partials);
  scan3_k<<<nb, 256, 0, stream>>>(deg, n, e, partials, rowptr, P, base8);
  k2_k<<<GZ + gE, 256, 0, stream>>>(x, W1f, Z3r, Z2, Z1, Z0, srcp, dstp, e, rank, base8, colb, n, GZ);

  int gHop = (n + 15) / 16;
  int gGemm = (n + 63) / 64;
  int gS16 = (n * 8 + 255) / 256;

  // ----- Layer 1 Horner: p2 = A(dis*z3raw) + z2 ; p1 = A p2 + z1 ; h1 = relu(A p1 + z0 + b1)
  hop_k<<<2 * gHop, 256, 0, stream>>>(Z3r, Z2, nullptr, T, rowptr, colb, dis, dis, n, gHop, 0);
  hop_k<<<2 * gHop, 256, 0, stream>>>(T, Z1, nullptr, Up, rowptr, colb, dis, nullptr, n, gHop, 0);
  hop_k<<<2 * gHop, 256, 0, stream>>>(Up, Z0, b1, h1, rowptr, colb, dis, nullptr, n, gHop, 1);
  gemm_last_k<<<gGemm, 256, 0, stream>>>(h1, W2f, dis, GB, GBs3, n);

  // ----- Layer 2 Horner at D=16: f2=A g3'+g2; f1=A f2'+g1; out=A f1'+g0+b2
  spmm16_k<<<gS16, 256, 0, stream>>>(GBs3, GB + 32, 64, nullptr, nullptr, F0, rowptr, colb, dis, n);
  spmm16_k<<<gS16, 256, 0, stream>>>(F0,   GB + 16, 64, nullptr, nullptr, F1, rowptr, colb, dis, n);
  spmm16_k<<<gS16, 256, 0, stream>>>(F1,   GB + 0,  64, b2, out, nullptr, rowptr, colb, dis, n);
}

// Round 16
// 385.137 us; speedup vs baseline: 1.1380x; 1.1380x over previous
//
#include <hip/hip_runtime.h>

#define DF 128

typedef __attribute__((ext_vector_type(8))) short bf16x8;
typedef __attribute__((ext_vector_type(4))) float f32x4;

__device__ __forceinline__ ushort f2bf(float f) {
  uint u = __float_as_uint(f);
  u += 0x7fff + ((u >> 16) & 1);
  return (ushort)(u >> 16);
}
__device__ __forceinline__ float bfl(uint v) { return __uint_as_float(v << 16); }
__device__ __forceinline__ float bfh(uint v) { return __uint_as_float(v & 0xffff0000u); }
__device__ __forceinline__ float b2f(ushort s) { return __uint_as_float(((uint)s) << 16); }

// ---------------- prepw (fragment-linear weights) + sentinel zeroing ----------------
__global__ __launch_bounds__(256) void prepw_k(const float* __restrict__ W1, const float* __restrict__ W2,
                                               ushort* __restrict__ W1f, ushort* __restrict__ W2f,
                                               ushort* __restrict__ Z3r, ushort* __restrict__ T,
                                               ushort* __restrict__ GBs3, ushort* __restrict__ F0,
                                               ushort* __restrict__ F1, int n) {
  int b = blockIdx.x, tid = threadIdx.x;
  if (b == 256) {       // zero sentinel rows (row n)
    if (tid < 128) {
      Z3r[(size_t)n * 128 + tid] = 0;
      T[(size_t)n * 128 + tid] = 0;
    }
    if (tid < 16) {
      GBs3[(size_t)n * 16 + tid] = 0;
      F0[(size_t)n * 16 + tid] = 0;
      F1[(size_t)n * 16 + tid] = 0;
    }
    return;
  }
  int t = b * 256 + tid;
  {
    int k = t >> 14, rem = t & 16383;
    int frag = rem >> 3, j = rem & 7;
    int nt = frag >> 8, ks = (frag >> 6) & 3, lane = frag & 63;
    int nn = nt * 16 + (lane & 15);
    int kk = ks * 32 + (lane >> 4) * 8 + j;
    W1f[t] = f2bf(W1[k * 16384 + kk * 128 + nn]);
  }
  if (t < 8192) {
    int frag = t >> 3, j = t & 7;
    int nt = frag >> 8, ks = (frag >> 6) & 3, lane = frag & 63;
    int kk = ks * 32 + (lane >> 4) * 8 + j;
    W2f[t] = f2bf(W2[nt * 2048 + kk * 16 + (lane & 15)]);
  }
}

// ---------------- K1: gemmZ blocks [0,GZ) | hist blocks (2 edges/thread, paired i and i+EH) ----------------
__global__ __launch_bounds__(256) void k1_k(const float* __restrict__ x, const ushort* __restrict__ W1f,
                                            ushort* __restrict__ Z3, ushort* __restrict__ Z2,
                                            ushort* __restrict__ Z1, ushort* __restrict__ Z0,
                                            const int* __restrict__ dst, int e, int EH,
                                            int* __restrict__ deg_s, int* __restrict__ rank,
                                            int n, int GZ) {
  int b = blockIdx.x, tid = threadIdx.x;
  if (b >= GZ) {                   // hist: 2 independent atomics in flight per thread
    int i0 = (b - GZ) * 256 + tid;
    int i1 = i0 + EH;
    int d0 = (i0 < e) ? dst[i0] : -1;
    int d1 = (i1 < e) ? dst[i1] : -1;
    int s0 = (i0 >> 8) & 7;
    int s1 = (i1 >> 8) & 7;        // == s0 since EH % 2048 == 0
    int r0 = 0, r1 = 0;
    if (d0 >= 0) r0 = atomicAdd(&deg_s[(size_t)s0 * n + d0], 1);
    if (d1 >= 0) r1 = atomicAdd(&deg_s[(size_t)s1 * n + d1], 1);
    if (d0 >= 0) rank[i0] = r0;
    if (d1 >= 0) rank[i1] = r1;
    return;
  }
  // gemmZ: 2 row-fragments per wave, per-nt accumulators (no LDS, low VGPR); Z3 stored RAW
  int wid = tid >> 6, lane = tid & 63;
  int l15 = lane & 15, kgrp = lane >> 4;
  int m0 = b * 128 + wid * 32 + l15;
  int m1 = m0 + 16;
  int mc0 = m0 < n ? m0 : n - 1;
  int mc1 = m1 < n ? m1 : n - 1;
  bf16x8 xf0[4], xf1[4];
#pragma unroll
  for (int ks = 0; ks < 4; ks++) {
    float4 a0 = *reinterpret_cast<const float4*>(x + (size_t)mc0 * 128 + ks * 32 + kgrp * 8);
    float4 a1 = *reinterpret_cast<const float4*>(x + (size_t)mc0 * 128 + ks * 32 + kgrp * 8 + 4);
    float4 b0 = *reinterpret_cast<const float4*>(x + (size_t)mc1 * 128 + ks * 32 + kgrp * 8);
    float4 b1v = *reinterpret_cast<const float4*>(x + (size_t)mc1 * 128 + ks * 32 + kgrp * 8 + 4);
    bf16x8 u, w;
    u[0] = (short)f2bf(a0.x); u[1] = (short)f2bf(a0.y); u[2] = (short)f2bf(a0.z); u[3] = (short)f2bf(a0.w);
    u[4] = (short)f2bf(a1.x); u[5] = (short)f2bf(a1.y); u[6] = (short)f2bf(a1.z); u[7] = (short)f2bf(a1.w);
    w[0] = (short)f2bf(b0.x); w[1] = (short)f2bf(b0.y); w[2] = (short)f2bf(b0.z); w[3] = (short)f2bf(b0.w);
    w[4] = (short)f2bf(b1v.x); w[5] = (short)f2bf(b1v.y); w[6] = (short)f2bf(b1v.z); w[7] = (short)f2bf(b1v.w);
    xf0[ks] = u; xf1[ks] = w;
  }
#pragma unroll
  for (int kk = 0; kk < 4; kk++) {
    const int k = 3 - kk;
    const ushort* Wk = W1f + (size_t)k * 16384;
    ushort* Out = (k == 3) ? Z3 : (k == 2) ? Z2 : (k == 1) ? Z1 : Z0;
#pragma unroll
    for (int nt = 0; nt < 8; nt++) {
      f32x4 acc0 = {0.f, 0.f, 0.f, 0.f}, acc1 = {0.f, 0.f, 0.f, 0.f};
#pragma unroll
      for (int ks = 0; ks < 4; ks++) {
        bf16x8 wf = *reinterpret_cast<const bf16x8*>(Wk + (size_t)((nt * 4 + ks) * 64 + lane) * 8);
        acc0 = __builtin_amdgcn_mfma_f32_16x16x32_bf16(wf, xf0[ks], acc0, 0, 0, 0);
        acc1 = __builtin_amdgcn_mfma_f32_16x16x32_bf16(wf, xf1[ks], acc1, 0, 0, 0);
      }
      int ncol = nt * 16 + kgrp * 4;
      if (m0 < n) {
        ushort4 st; st.x = f2bf(acc0[0]); st.y = f2bf(acc0[1]);
        st.z = f2bf(acc0[2]); st.w = f2bf(acc0[3]);
        *reinterpret_cast<ushort4*>(Out + (size_t)m0 * 128 + ncol) = st;
      }
      if (m1 < n) {
        ushort4 st; st.x = f2bf(acc1[0]); st.y = f2bf(acc1[1]);
        st.z = f2bf(acc1[2]); st.w = f2bf(acc1[3]);
        *reinterpret_cast<ushort4*>(Out + (size_t)m1 * 128 + ncol) = st;
      }
    }
  }
}

// ---------------- fused reduce + scan1 ----------------
__global__ __launch_bounds__(256) void rs1_k(const int* __restrict__ deg_s, int n,
                                             int* __restrict__ deg, int* __restrict__ P,
                                             float* __restrict__ dis, int* __restrict__ partials) {
  __shared__ int sm[256];
  int tid = threadIdx.x;
  int base = blockIdx.x * 1024;
  int s = 0;
#pragma unroll
  for (int j = 0; j < 4; j++) {
    int idx = base + tid * 4 + j;
    if (idx < n) {
      int run = 0;
#pragma unroll
      for (int sh = 0; sh < 8; sh++) {
        int v = deg_s[(size_t)sh * n + idx];
        P[(size_t)sh * n + idx] = run;
        run += v;
      }
      deg[idx] = run;
      dis[idx] = run > 0 ? rsqrtf((float)run) : 0.f;
      s += run;
    }
  }
  sm[tid] = s; __syncthreads();
  for (int off = 128; off > 0; off >>= 1) {
    if (tid < off) sm[tid] += sm[tid + off];
    __syncthreads();
  }
  if (tid == 0) partials[blockIdx.x] = sm[0];
}

// scan3 (self-scans partials) + build base8[sh][d] = rowptr[d] + P[sh][d]
__global__ __launch_bounds__(256) void scan3_k(const int* __restrict__ deg, int n, int e,
                                               const int* __restrict__ partials,
                                               int* __restrict__ rowptr,
                                               const int* __restrict__ P, int* __restrict__ base8) {
  __shared__ int sm[256];
  __shared__ int pp[256];
  int tid = threadIdx.x;
  int pre = 0;
  for (int i = tid; i < blockIdx.x; i += 256) pre += partials[i];
  pp[tid] = pre; __syncthreads();
  for (int off = 128; off > 0; off >>= 1) {
    if (tid < off) pp[tid] += pp[tid + off];
    __syncthreads();
  }
  int blockbase = pp[0];
  int base = blockIdx.x * 1024;
  int loc[4]; int s = 0;
#pragma unroll
  for (int j = 0; j < 4; j++) {
    int idx = base + tid * 4 + j;
    int v = (idx < n) ? deg[idx] : 0;
    loc[j] = s; s += v;
  }
  sm[tid] = s; __syncthreads();
  int tsum = s;
  for (int off = 1; off < 256; off <<= 1) {
    int v = (tid >= (unsigned)off) ? sm[tid - off] : 0;
    __syncthreads();
    sm[tid] += v;
    __syncthreads();
  }
  int excl = sm[tid] - tsum + blockbase;
#pragma unroll
  for (int j = 0; j < 4; j++) {
    int idx = base + tid * 4 + j;
    if (idx < n) {
      int rp = excl + loc[j];
      rowptr[idx] = rp;
#pragma unroll
      for (int sh = 0; sh < 8; sh++)
        base8[(size_t)sh * n + idx] = rp + P[(size_t)sh * n + idx];
    }
  }
  if (blockIdx.x == 0 && tid == 0) rowptr[n] = e;
}

// ---------------- K2: csr_fill (blocks < gE) | in-place scale Z3 *= dis ----------------
__global__ __launch_bounds__(256) void k2_k(const int* __restrict__ src, const int* __restrict__ dst, int e,
                                            const int* __restrict__ rank, const int* __restrict__ base8,
                                            int* __restrict__ colb,
                                            ushort* __restrict__ Z3, const float* __restrict__ dis,
                                            int n, int gE) {
  int b = blockIdx.x, tid = threadIdx.x;
  if (b < gE) {
    int i = b * 256 + tid;
    if (i < e) {
      int d = dst[i];
      int shard = (i >> 8) & 7;
      int p = base8[(size_t)shard * n + d] + rank[i];
      colb[p] = src[i];
    }
  } else {
    int u = (b - gE) * 256 + tid;     // over n*16 8-col segments
    int i = u >> 4, seg = u & 15;
    if (i < n) {
      float d = dis[i];
      ushort* p = Z3 + (size_t)i * 128 + seg * 8;
      uint4 v = *reinterpret_cast<const uint4*>(p);
      uint4 o;
      o.x = (uint)f2bf(d * bfl(v.x)) | ((uint)f2bf(d * bfh(v.x)) << 16);
      o.y = (uint)f2bf(d * bfl(v.y)) | ((uint)f2bf(d * bfh(v.y)) << 16);
      o.z = (uint)f2bf(d * bfl(v.z)) | ((uint)f2bf(d * bfh(v.z)) << 16);
      o.w = (uint)f2bf(d * bfl(v.w)) | ((uint)f2bf(d * bfh(v.w)) << 16);
      *reinterpret_cast<uint4*>(p) = o;
    }
  }
}

// ---------------- hop: both col-halves in one launch; unroll-16 gather ----------------
__global__ __launch_bounds__(256) void hop_k(const ushort* __restrict__ hin, const ushort* __restrict__ zk,
                                             const float* __restrict__ b1, ushort* __restrict__ hout,
                                             const int* __restrict__ rowptr, const int* __restrict__ colb,
                                             const float* __restrict__ dis, int n, int gHop, int last) {
  int colhalf = blockIdx.x >= gHop ? 1 : 0;
  int nb = blockIdx.x - colhalf * gHop;
  int node = nb * 16 + (threadIdx.x >> 4);
  int gl = threadIdx.x & 15;
  if (node >= n) return;
  int cbase = colhalf * 64 + gl * 4;
  int e0 = rowptr[node], e1 = rowptr[node + 1];
  float a0 = 0.f, a1 = 0.f, a2 = 0.f, a3 = 0.f;
  for (int ee = e0; ee < e1; ee += 16) {
    int c[16];
#pragma unroll
    for (int j = 0; j < 16; j++) {
      int idx = ee + j;
      c[j] = idx < e1 ? colb[idx] : n;      // row n is all-zero sentinel
    }
    uint2 v[16];
#pragma unroll
    for (int j = 0; j < 16; j++)
      v[j] = *reinterpret_cast<const uint2*>(hin + (size_t)c[j] * 128 + cbase);
#pragma unroll
    for (int j = 0; j < 16; j++) {
      a0 += bfl(v[j].x); a1 += bfh(v[j].x);
      a2 += bfl(v[j].y); a3 += bfh(v[j].y);
    }
  }
  float d = dis[node];
  uint2 zr = *reinterpret_cast<const uint2*>(zk + (size_t)node * 128 + cbase);
  float t0 = fmaf(d, a0, bfl(zr.x)), t1 = fmaf(d, a1, bfh(zr.x));
  float t2 = fmaf(d, a2, bfl(zr.y)), t3 = fmaf(d, a3, bfh(zr.y));
  uint2 st;
  if (last) {
    float4 bv = *reinterpret_cast<const float4*>(b1 + cbase);
    t0 = fmaxf(t0 + bv.x, 0.f); t1 = fmaxf(t1 + bv.y, 0.f);
    t2 = fmaxf(t2 + bv.z, 0.f); t3 = fmaxf(t3 + bv.w, 0.f);
    st.x = (uint)f2bf(t0) | ((uint)f2bf(t1) << 16);
    st.y = (uint)f2bf(t2) | ((uint)f2bf(t3) << 16);
  } else {
    st.x = (uint)f2bf(d * t0) | ((uint)f2bf(d * t1) << 16);
    st.y = (uint)f2bf(d * t2) | ((uint)f2bf(d * t3) << 16);
  }
  *reinterpret_cast<uint2*>(hout + (size_t)node * 128 + cbase) = st;
}

// ---------------- final GEMM: GB = h1 @ W2pack (raw) + GBs3 = dis * g3 ----------------
__global__ __launch_bounds__(256) void gemm_last_k(const ushort* __restrict__ h1, const ushort* __restrict__ W2f,
                                                   const float* __restrict__ dis,
                                                   ushort* __restrict__ GB, ushort* __restrict__ GBs3, int n) {
  int wid = threadIdx.x >> 6, lane = threadIdx.x & 63;
  int kgrp = lane >> 4;
  int m = blockIdx.x * 64 + wid * 16 + (lane & 15);
  int mc = m < n ? m : n - 1;
  float dm = dis[mc];
  bf16x8 xf[4];
#pragma unroll
  for (int ks = 0; ks < 4; ks++)
    xf[ks] = *reinterpret_cast<const bf16x8*>(h1 + (size_t)mc * 128 + ks * 32 + kgrp * 8);
#pragma unroll
  for (int nt = 0; nt < 4; nt++) {
    f32x4 acc = {0.f, 0.f, 0.f, 0.f};
#pragma unroll
    for (int ks = 0; ks < 4; ks++) {
      bf16x8 wf = *reinterpret_cast<const bf16x8*>(W2f + (size_t)((nt * 4 + ks) * 64 + lane) * 8);
      acc = __builtin_amdgcn_mfma_f32_16x16x32_bf16(wf, xf[ks], acc, 0, 0, 0);
    }
    if (m < n) {
      int ncol = nt * 16 + kgrp * 4;
      ushort4 st; st.x = f2bf(acc[0]); st.y = f2bf(acc[1]); st.z = f2bf(acc[2]); st.w = f2bf(acc[3]);
      *reinterpret_cast<ushort4*>(GB + (size_t)m * 64 + ncol) = st;
      if (nt == 3) {
        ushort4 ss; ss.x = f2bf(dm * acc[0]); ss.y = f2bf(dm * acc[1]);
        ss.z = f2bf(dm * acc[2]); ss.w = f2bf(dm * acc[3]);
        *reinterpret_cast<ushort4*>(GBs3 + (size_t)m * 16 + kgrp * 4) = ss;
      }
    }
  }
}

// ---------------- SpMM D=16: unroll-8 ----------------
__global__ __launch_bounds__(256) void spmm16_k(const ushort* __restrict__ in,
                                                const ushort* __restrict__ addraw, int addstride,
                                                const float* __restrict__ b2,
                                                float* __restrict__ outf, ushort* __restrict__ outb,
                                                const int* __restrict__ rowptr, const int* __restrict__ colb,
                                                const float* __restrict__ dis, int n) {
  int t = blockIdx.x * 256 + threadIdx.x;
  int node = t >> 3, cp = t & 7;
  if (node >= n) return;
  int e0 = rowptr[node], e1 = rowptr[node + 1];
  float a0 = 0.f, a1 = 0.f;
  for (int ee = e0; ee < e1; ee += 8) {
    int c[8];
#pragma unroll
    for (int j = 0; j < 8; j++) {
      int idx = ee + j;
      c[j] = idx < e1 ? colb[idx] : n;
    }
    uint v[8];
#pragma unroll
    for (int j = 0; j < 8; j++)
      v[j] = *reinterpret_cast<const uint*>(in + (size_t)c[j] * 16 + cp * 2);
#pragma unroll
    for (int j = 0; j < 8; j++) { a0 += bfl(v[j]); a1 += bfh(v[j]); }
  }
  float d = dis[node];
  uint av = *reinterpret_cast<const uint*>(addraw + (size_t)node * addstride + cp * 2);
  float t0 = fmaf(d, a0, b2f((ushort)(av & 0xffff)));
  float t1 = fmaf(d, a1, b2f((ushort)(av >> 16)));
  if (outf) {
    float2 st; st.x = t0 + b2[cp * 2]; st.y = t1 + b2[cp * 2 + 1];
    *reinterpret_cast<float2*>(outf + (size_t)node * 16 + cp * 2) = st;
  } else {
    uint pk = (uint)f2bf(d * t0) | ((uint)f2bf(d * t1) << 16);
    *reinterpret_cast<uint*>(outb + (size_t)node * 16 + cp * 2) = pk;
  }
}

extern "C" void kernel_launch(void* const* d_in, const int* in_sizes, int n_in,
                              void* d_out, int out_size, void* d_ws, size_t ws_size,
                              hipStream_t stream) {
  const float* x  = (const float*)d_in[0];
  const int*   ei = (const int*)d_in[1];
  const float* W1 = (const float*)d_in[2];
  const float* b1 = (const float*)d_in[3];
  const float* W2 = (const float*)d_in[4];
  const float* b2 = (const float*)d_in[5];
  float* out = (float*)d_out;

  const int n = in_sizes[0] / DF;
  const int e = in_sizes[1] / 2;
  const int* srcp = ei;
  const int* dstp = ei + e;

  char* ws = (char*)d_ws;
  size_t off = 0;
  auto alloc = [&](size_t bytes) -> void* {
    void* p = ws + off;
    off += (bytes + 255) & ~(size_t)255;
    return p;
  };
  ushort* Z3r  = (ushort*)alloc((size_t)(n + 1) * 128 * 2); // z3 raw -> scaled in k2; then hop2 out
  ushort* T    = (ushort*)alloc((size_t)(n + 1) * 128 * 2); // hop1 out; then h1 (hop3 out)
  ushort* Z2   = (ushort*)alloc((size_t)n * 128 * 2);       // later GB (n x 64)
  ushort* Z1   = (ushort*)alloc((size_t)n * 128 * 2);
  ushort* Z0   = (ushort*)alloc((size_t)n * 128 * 2);
  int*   deg_s = (int*)alloc((size_t)8 * n * 4);            // sharded hist; later base8
  int*   P     = (int*)alloc((size_t)8 * n * 4);
  int*   deg   = (int*)alloc((size_t)n * 4);
  float* dis   = (float*)alloc((size_t)n * 4);
  int*   rowptr= (int*)alloc((size_t)(n + 1) * 4);
  int*   rank  = (int*)alloc((size_t)e * 4);
  int*   partials = (int*)alloc(1024 * 4);
  int*   colb  = (int*)alloc((size_t)e * 4);
  ushort* W1f  = (ushort*)alloc(4 * 128 * 128 * 2);
  ushort* W2f  = (ushort*)alloc(64 * 128 * 2);
  ushort* GBs3 = (ushort*)alloc((size_t)(n + 1) * 16 * 2);
  ushort* F0   = (ushort*)alloc((size_t)(n + 1) * 16 * 2);
  ushort* F1   = (ushort*)alloc((size_t)(n + 1) * 16 * 2);
  // aliases
  ushort* Up = Z3r;   // hop2 output (Z3r consumed by hop1)
  ushort* h1 = T;     // hop3 output (T consumed by hop2)
  ushort* GB = Z2;    // gemm_last output (Z2 consumed by hop1's zk)
  int* base8 = deg_s; // scan3 output (deg_s dead after rs1)

  hipMemsetAsync(deg_s, 0, (size_t)8 * n * 4, stream);

  int gE = (e + 255) / 256;
  int nb = (n + 1023) / 1024;
  int GZ = (n + 127) / 128;
  int EH = ((e / 2 + 2047) / 2048) * 2048;    // pair stride, multiple of 2048 (keeps shard affinity)
  int nh = EH / 256;                          // hist blocks (2 edges/thread)

  prepw_k<<<257, 256, 0, stream>>>(W1, W2, W1f, W2f, Z3r, T, GBs3, F0, F1, n);
  k1_k<<<GZ + nh, 256, 0, stream>>>(x, W1f, Z3r, Z2, Z1, Z0, dstp, e, EH, deg_s, rank, n, GZ);
  rs1_k<<<nb, 256, 0, stream>>>(deg_s, n, deg, P, dis, partials);
  scan3_k<<<nb, 256, 0, stream>>>(deg, n, e, partials, rowptr, P, base8);
  int gScale = (n * 16 + 255) / 256;
  k2_k<<<gE + gScale, 256, 0, stream>>>(srcp, dstp, e, rank, base8, colb, Z3r, dis, n, gE);

  int gHop = (n + 15) / 16;
  int gGemm = (n + 63) / 64;
  int gS16 = (n * 8 + 255) / 256;

  // ----- Layer 1 Horner (merged half-col hops): p3=z3'; p2=A p3+z2; p1=A p2+z1; h1=relu(A p1+z0+b1)
  hop_k<<<2 * gHop, 256, 0, stream>>>(Z3r, Z2, nullptr, T, rowptr, colb, dis, n, gHop, 0);
  hop_k<<<2 * gHop, 256, 0, stream>>>(T, Z1, nullptr, Up, rowptr, colb, dis, n, gHop, 0);
  hop_k<<<2 * gHop, 256, 0, stream>>>(Up, Z0, b1, h1, rowptr, colb, dis, n, gHop, 1);
  gemm_last_k<<<gGemm, 256, 0, stream>>>(h1, W2f, dis, GB, GBs3, n);

  // ----- Layer 2 Horner at D=16: f2=A g3'+g2; f1=A f2'+g1; out=A f1'+g0+b2
  spmm16_k<<<gS16, 256, 0, stream>>>(GBs3, GB + 32, 64, nullptr, nullptr, F0, rowptr, colb, dis, n);
  spmm16_k<<<gS16, 256, 0, stream>>>(F0,   GB + 16, 64, nullptr, nullptr, F1, rowptr, colb, dis, n);
  spmm16_k<<<gS16, 256, 0, stream>>>(F1,   GB + 0,  64, b2, out, nullptr, rowptr, colb, dis, n);
}